// Round 1
// baseline (266.425 us; speedup 1.0000x reference)
//
#include <hip/hip_runtime.h>
#include <hip/hip_bf16.h>
#include <math.h>

// Problem constants (match reference)
#define BATCH   65536
#define DIMD    128
#define NCLS    10
#define NSENS   2
#define NBLOCKS 2048   // main-kernel grid; 2048*3 doubles of ws partials

// Butterfly reductions over a 32-lane half-wave (xor masks 16..1 stay within
// each 32-lane group of the 64-lane wave -> two independent rows per wave).
__device__ __forceinline__ float half32_max(float v) {
    #pragma unroll
    for (int m = 16; m >= 1; m >>= 1) v = fmaxf(v, __shfl_xor(v, m, 64));
    return v;
}

// KL(batchmean) row term for one 128-wide row handled by a 32-lane half:
//   enc = mu + exp(0.5*ls)*eps ; prior = pr (softmax is shift-invariant,
//   so the "+1" on prior_s cancels and is omitted)
//   KL = sum_j t_j*(e_j - p_j) - lse(e) + lse(p),  t = softmax(enc)
__device__ __forceinline__ float kl_row(float4 mu, float4 ls, float4 ep, float4 pr) {
    float e0 = mu.x + __expf(0.5f * ls.x) * ep.x;
    float e1 = mu.y + __expf(0.5f * ls.y) * ep.y;
    float e2 = mu.z + __expf(0.5f * ls.z) * ep.z;
    float e3 = mu.w + __expf(0.5f * ls.w) * ep.w;

    float me = fmaxf(fmaxf(e0, e1), fmaxf(e2, e3));
    float mp = fmaxf(fmaxf(pr.x, pr.y), fmaxf(pr.z, pr.w));
    #pragma unroll
    for (int m = 16; m >= 1; m >>= 1) {
        me = fmaxf(me, __shfl_xor(me, m, 64));
        mp = fmaxf(mp, __shfl_xor(mp, m, 64));
    }

    float xe0 = __expf(e0 - me), xe1 = __expf(e1 - me);
    float xe2 = __expf(e2 - me), xe3 = __expf(e3 - me);
    float xp0 = __expf(pr.x - mp), xp1 = __expf(pr.y - mp);
    float xp2 = __expf(pr.z - mp), xp3 = __expf(pr.w - mp);

    float Ze = xe0 + xe1 + xe2 + xe3;
    float Zp = xp0 + xp1 + xp2 + xp3;
    float S  = xe0 * (e0 - pr.x) + xe1 * (e1 - pr.y)
             + xe2 * (e2 - pr.z) + xe3 * (e3 - pr.w);
    #pragma unroll
    for (int m = 16; m >= 1; m >>= 1) {
        Ze += __shfl_xor(Ze, m, 64);
        Zp += __shfl_xor(Zp, m, 64);
        S  += __shfl_xor(S,  m, 64);
    }

    float lse_e = me + __logf(Ze);
    float lse_p = mp + __logf(Zp);
    return S / Ze - lse_e + lse_p;
}

__global__ __launch_bounds__(256) void crit_main(
    const float* __restrict__ mean_t,      const float* __restrict__ mean_s,
    const float* __restrict__ log_std_t,   const float* __restrict__ log_std_s,
    const float* __restrict__ y_zt,        const float* __restrict__ s_zt,
    const float* __restrict__ eps_prior_t, const float* __restrict__ eps_prior_s,
    const float* __restrict__ eps_t,       const float* __restrict__ eps_s,
    const int*   __restrict__ target,
    double*      __restrict__ ws_partial)
{
    const int tid  = threadIdx.x;
    const int lane = tid & 63;
    const int sub  = lane & 31;   // lane within the 32-lane half (one row)
    const int half = lane >> 5;   // which of the wave's 2 rows
    const int gwave = blockIdx.x * 4 + (tid >> 6);
    const int totalWaves = gridDim.x * 4;
    const int nPairs = BATCH / 2;

    double acc_ce = 0.0, acc_H = 0.0, acc_kl = 0.0;

    for (int pair = gwave; pair < nPairs; pair += totalWaves) {
        // float4 index: wave covers floats [pair*256, pair*256+256) = 2 rows
        const int fidx = pair * 64 + lane;

        float4 mu = ((const float4*)mean_t)[fidx];
        float4 ls = ((const float4*)log_std_t)[fidx];
        float4 ep = ((const float4*)eps_t)[fidx];
        float4 pr = ((const float4*)eps_prior_t)[fidx];
        float kl_t = kl_row(mu, ls, ep, pr);

        mu = ((const float4*)mean_s)[fidx];
        ls = ((const float4*)log_std_s)[fidx];
        ep = ((const float4*)eps_s)[fidx];
        pr = ((const float4*)eps_prior_s)[fidx];
        float kl_s = kl_row(mu, ls, ep, pr);

        if (sub == 0) {
            const int r = pair * 2 + half;

            // --- cross entropy on 10-class logits (row is 8B-aligned) ---
            const float* yr = y_zt + (size_t)r * NCLS;
            float2 y01 = *(const float2*)(yr + 0);
            float2 y23 = *(const float2*)(yr + 2);
            float2 y45 = *(const float2*)(yr + 4);
            float2 y67 = *(const float2*)(yr + 6);
            float2 y89 = *(const float2*)(yr + 8);
            float m = fmaxf(fmaxf(fmaxf(y01.x, y01.y), fmaxf(y23.x, y23.y)),
                            fmaxf(fmaxf(y45.x, y45.y),
                                  fmaxf(fmaxf(y67.x, y67.y), fmaxf(y89.x, y89.y))));
            float Z = __expf(y01.x - m) + __expf(y01.y - m)
                    + __expf(y23.x - m) + __expf(y23.y - m)
                    + __expf(y45.x - m) + __expf(y45.y - m)
                    + __expf(y67.x - m) + __expf(y67.y - m)
                    + __expf(y89.x - m) + __expf(y89.y - m);
            float lse = m + __logf(Z);
            int   t   = target[r];
            float yt  = yr[t];
            float ce  = lse - yt;

            // --- entropy of 2-class softmax ---
            float2 s2 = *(const float2*)(s_zt + (size_t)r * NSENS);
            float ms  = fmaxf(s2.x, s2.y);
            float za  = __expf(s2.x - ms), zb = __expf(s2.y - ms);
            float Zs  = za + zb;
            float lses = ms + __logf(Zs);
            float pa = za / Zs, pb = zb / Zs;
            float H  = -(pa * (s2.x - lses) + pb * (s2.y - lses));

            acc_ce += (double)ce;
            acc_H  += (double)H;
            acc_kl += (double)kl_t + (double)kl_s;
        }
    }

    // 8 contributing lanes per block (sub==0 of each half of each of 4 waves)
    __shared__ double sh[8][3];
    if (sub == 0) {
        const int slot = tid >> 5;   // 0..7
        sh[slot][0] = acc_ce;
        sh[slot][1] = acc_H;
        sh[slot][2] = acc_kl;
    }
    __syncthreads();
    if (tid == 0) {
        double c = 0.0, h = 0.0, k = 0.0;
        #pragma unroll
        for (int i = 0; i < 8; ++i) { c += sh[i][0]; h += sh[i][1]; k += sh[i][2]; }
        ws_partial[blockIdx.x * 3 + 0] = c;
        ws_partial[blockIdx.x * 3 + 1] = h;
        ws_partial[blockIdx.x * 3 + 2] = k;
    }
}

__global__ __launch_bounds__(256) void crit_reduce(
    const double* __restrict__ ws_partial,
    const int*    __restrict__ step_ptr,
    float*        __restrict__ out,
    int nblocks)
{
    const int tid = threadIdx.x;
    double c = 0.0, h = 0.0, k = 0.0;
    for (int i = tid; i < nblocks; i += 256) {
        c += ws_partial[3 * i + 0];
        h += ws_partial[3 * i + 1];
        k += ws_partial[3 * i + 2];
    }
    __shared__ double sc[256], sh_[256], sk[256];
    sc[tid] = c; sh_[tid] = h; sk[tid] = k;
    __syncthreads();
    for (int s = 128; s > 0; s >>= 1) {
        if (tid < s) { sc[tid] += sc[tid + s]; sh_[tid] += sh_[tid + s]; sk[tid] += sk[tid + s]; }
        __syncthreads();
    }
    if (tid == 0) {
        double frac  = (double)step_ptr[0] / 1000.0;   // STEP_SIZE
        double lam_e  = 0.1   * exp2(frac);            // LAMBDA_E * GAMMA_E^frac
        double lam_od = 0.036 * exp2(frac);            // LAMBDA_OD * GAMMA_OD^frac
        out[0] = (float)((sc[0] + lam_e * sh_[0] + lam_od * sk[0]) / (double)BATCH);
    }
}

extern "C" void kernel_launch(void* const* d_in, const int* in_sizes, int n_in,
                              void* d_out, int out_size, void* d_ws, size_t ws_size,
                              hipStream_t stream) {
    const float* mean_t      = (const float*)d_in[0];
    const float* mean_s      = (const float*)d_in[1];
    const float* log_std_t   = (const float*)d_in[2];
    const float* log_std_s   = (const float*)d_in[3];
    const float* y_zt        = (const float*)d_in[4];
    const float* s_zt        = (const float*)d_in[5];
    const float* eps_prior_t = (const float*)d_in[6];
    const float* eps_prior_s = (const float*)d_in[7];
    const float* eps_t       = (const float*)d_in[8];
    const float* eps_s       = (const float*)d_in[9];
    const int*   target      = (const int*)d_in[10];
    const int*   step_ptr    = (const int*)d_in[11];

    double* ws_partial = (double*)d_ws;   // NBLOCKS*3 doubles = 48 KiB
    float*  out        = (float*)d_out;

    crit_main<<<NBLOCKS, 256, 0, stream>>>(
        mean_t, mean_s, log_std_t, log_std_s, y_zt, s_zt,
        eps_prior_t, eps_prior_s, eps_t, eps_s, target, ws_partial);
    crit_reduce<<<1, 256, 0, stream>>>(ws_partial, step_ptr, out, NBLOCKS);
}